// Round 3
// baseline (244.707 us; speedup 1.0000x reference)
//
#include <hip/hip_runtime.h>

// Problem constants (from reference)
#define NB    32
#define KJ    17
#define CIN   2048
#define HWSZ  4096     // H*W = 64*64
#define WDIM  64
#define CEMB  2112     // 64 + 2048
#define HID   128
#define NROWS (NB*KJ)  // 544
#define SPLITK 4
#define NBLK  256      // fused grid: one block per CU, co-resident
#define NTHR  512

// Skeleton adjacency mask (H36M edges + diagonal), row i -> bitmask over j
__device__ __constant__ unsigned c_mask[KJ] = {
  0x00093u, 0x00007u, 0x0000Eu, 0x0000Cu, 0x00031u, 0x00070u, 0x00060u,
  0x00181u, 0x04B80u, 0x00700u, 0x00600u, 0x01900u, 0x03800u, 0x03000u,
  0x0C100u, 0x1C000u, 0x18000u
};

// ---------------------------------------------------------------------------
// k_init: reset the grid-barrier counter (fresh every launch -> deterministic,
// immune to the 0xAA workspace poison).
// ---------------------------------------------------------------------------
__global__ void k_init(unsigned* cnt) {
  if (threadIdx.x == 0) *cnt = 0u;
}

// Grid-wide barrier: one arrival per block, device-scope fences.
// If cnt starts above target (e.g. profiler replays without k_init) it
// degenerates to a pass-through instead of hanging.
__device__ __forceinline__ void gbar(unsigned* cnt, unsigned target) {
  __syncthreads();
  if (threadIdx.x == 0) {
    __threadfence();                       // release: publish stage writes
    atomicAdd(cnt, 1u);                    // device-scope by default
    while (__hip_atomic_load(cnt, __ATOMIC_RELAXED, __HIP_MEMORY_SCOPE_AGENT)
           < target) {
      __builtin_amdgcn_s_sleep(2);
    }
    __threadfence();                       // acquire: invalidate stale caches
  }
  __syncthreads();
}

// ---------------------------------------------------------------------------
// Fused pipeline: argmax+posemb | gather | input GEMM | GCN stack
// grid = 256 blocks x 512 threads, grid barriers between stages.
// ---------------------------------------------------------------------------
__device__ __forceinline__ void layer_compute(
    const float (*S)[HID], const float* __restrict__ Wl,
    float (*O0)[HID], float (*O1)[HID], int t) {
  const int q = t >> 7;
  const int j = t & 127;
  const int r0 = q * 5;                 // rows r0..r0+4 (rows 17..19 are pad)
  const float* W0 = Wl + j;             // W[0][c][j], stride HID over c
  const float* W1 = Wl + HID * HID + j; // W[1][c][j]
  float a0[5], a1[5];
  #pragma unroll
  for (int r = 0; r < 5; ++r) { a0[r] = 0.f; a1[r] = 0.f; }
  #pragma unroll 4
  for (int c = 0; c < HID; c += 4) {
    const float w00 = W0[(c + 0) * HID], w01 = W0[(c + 1) * HID];
    const float w02 = W0[(c + 2) * HID], w03 = W0[(c + 3) * HID];
    const float w10 = W1[(c + 0) * HID], w11 = W1[(c + 1) * HID];
    const float w12 = W1[(c + 2) * HID], w13 = W1[(c + 3) * HID];
    #pragma unroll
    for (int r = 0; r < 5; ++r) {
      const float4 s = *(const float4*)(&S[r0 + r][c]);   // wave-uniform broadcast
      a0[r] = fmaf(s.x, w00, fmaf(s.y, w01, fmaf(s.z, w02, fmaf(s.w, w03, a0[r]))));
      a1[r] = fmaf(s.x, w10, fmaf(s.y, w11, fmaf(s.z, w12, fmaf(s.w, w13, a1[r]))));
    }
  }
  #pragma unroll
  for (int r = 0; r < 5; ++r) { O0[r0 + r][j] = a0[r]; O1[r0 + r][j] = a1[r]; }
}

template <int ADD>
__device__ __forceinline__ void mix_bn(
    const float (*T0)[HID], const float (*T1)[HID], const float (*A)[KJ],
    const float* __restrict__ bias, const float* __restrict__ gamma,
    const float* __restrict__ beta, float (*dst)[HID], int t) {
  const int d = t & 127;
  const int q = t >> 7;
  const float bsv = bias[d];
  const float gsv = gamma[d] * 0.99999500003749969f;  // rsqrt(1+1e-5)
  const float btv = beta[d];
  for (int i = q; i < KJ; i += 4) {
    float s = 0.f;
    #pragma unroll
    for (int jj = 0; jj < KJ; ++jj) s = fmaf(A[i][jj], T1[jj][d], s);
    s += A[i][i] * (T0[i][d] - T1[i][d]);   // replace diag term h1 -> h0
    const float v = fmaxf(fmaf(s + bsv, gsv, btv), 0.f);
    if (ADD) dst[i][d] += v; else dst[i][d] = v;
  }
}

__global__ __launch_bounds__(NTHR, 1) void k_fused(
    const float* __restrict__ x, const float* __restrict__ heatmap,
    const float* __restrict__ bbox, const float* __restrict__ pos_w,
    const float* __restrict__ pos_b, const float* __restrict__ Wi,
    const float* __restrict__ bi, const float* __restrict__ Ei,
    const float* __restrict__ gi, const float* __restrict__ bti,
    const float* __restrict__ Wh, const float* __restrict__ bh,
    const float* __restrict__ Eh, const float* __restrict__ gh,
    const float* __restrict__ bth, const float* __restrict__ Wo,
    const float* __restrict__ bo, const float* __restrict__ Eo,
    unsigned* __restrict__ cnt, int* __restrict__ locs,
    float* __restrict__ h_ws, float* __restrict__ part,
    float* __restrict__ out) {
  __shared__ float adjm[10][KJ][KJ];
  __shared__ float Hs[20][HID], Rs[20][HID], T0s[20][HID], T1s[20][HID];
  __shared__ float svals[NTHR];
  __shared__ int   sidx[NTHR];
  __shared__ float Atile[20][48];

  const int t = threadIdx.x;
  const int blk = blockIdx.x;

  // ---------------- Stage A: argmax + posemb -> locs, h[:,0:64] ------------
  for (int kp = blk; kp < NROWS; kp += NBLK) {
    const int n = kp / KJ;
    const float4* hm4 = (const float4*)(heatmap + (size_t)kp * HWSZ);
    float best = -1e30f; int bidx = 0;
    #pragma unroll
    for (int kk = 0; kk < 2; ++kk) {
      const int vi = kk * NTHR + t;
      const float4 v = hm4[vi];
      const int base = vi * 4;
      if (v.x > best) { best = v.x; bidx = base;     }
      if (v.y > best) { best = v.y; bidx = base + 1; }
      if (v.z > best) { best = v.z; bidx = base + 2; }
      if (v.w > best) { best = v.w; bidx = base + 3; }
    }
    svals[t] = best; sidx[t] = bidx;
    __syncthreads();
    for (int s = NTHR / 2; s > 0; s >>= 1) {
      if (t < s) {
        const float v2 = svals[t + s]; const int i2 = sidx[t + s];
        if (v2 > svals[t] || (v2 == svals[t] && i2 < sidx[t])) {
          svals[t] = v2; sidx[t] = i2;
        }
      }
      __syncthreads();
    }
    const int loc = sidx[0];
    if (t == 0) locs[kp] = loc;
    if (t < 64) {
      const float kx = (float)(loc & (WDIM - 1));
      const float ky = (float)(loc >> 6);
      float in6[6];
      in6[0] = kx * (2.0f / 64.0f) - 1.0f;
      in6[1] = ky * (2.0f / 64.0f) - 1.0f;
      in6[2] = bbox[n * 4 + 0] * (2.0f / 1920.0f) - 1.0f;
      in6[3] = bbox[n * 4 + 1] * (2.0f / 1080.0f) - 1.0f;
      in6[4] = bbox[n * 4 + 2] * (1.0f / 1920.0f);
      in6[5] = bbox[n * 4 + 3] * (1.0f / 1080.0f);
      float acc = pos_b[t];
      #pragma unroll
      for (int c = 0; c < 6; ++c) acc = fmaf(in6[c], pos_w[c * 64 + t], acc);
      h_ws[(size_t)kp * CEMB + t] = acc;
    }
    __syncthreads();
  }
  gbar(cnt, NBLK);          // locs + posemb visible

  // ---------------- Stage B: scattered feature gather -> h[:,64:2112] -----
  {
    const int total = NROWS * CIN;        // 1,114,112
    for (int idx = blk * NTHR + t; idx < total; idx += NBLK * NTHR) {
      const int b = idx >> 11;            // /2048
      const int c = idx & 2047;
      const int n = b / KJ;
      const int loc = locs[b];
      const float v = x[((size_t)(n * CIN + c)) * HWSZ + loc];
      h_ws[(size_t)b * CEMB + 64 + c] = v;
    }
  }
  gbar(cnt, 2 * NBLK);      // h complete

  // ---------------- Stage C: input GEMM, 256 jobs = (n, colhalf, ksplit) --
  {
    const int n  = blk >> 3;              // 0..31
    const int bn = (blk >> 2) & 1;        // col half: 0 -> cols 0..127, 1 -> 128..255
    const int z  = blk & 3;               // K quarter (528 each)
    const int jj = t & 127;
    const int g  = t >> 7;                // row group: 5 rows each (padded)
    const int rbase = g * 5;
    const float* W = Wi + (size_t)bn * CEMB * HID + jj;
    const int k0 = z * 528;

    float acc[5] = {0.f, 0.f, 0.f, 0.f, 0.f};
    for (int ch = 0; ch < 11; ++ch) {     // 11 chunks x 48
      const int kk = k0 + ch * 48;
      __syncthreads();
      for (int idx = t; idx < KJ * 48; idx += NTHR) {
        const int r = idx / 48, c = idx - r * 48;
        Atile[r][c] = h_ws[(size_t)(n * KJ + r) * CEMB + kk + c];
      }
      __syncthreads();
      #pragma unroll 3
      for (int c = 0; c < 48; c += 4) {
        const float w0 = W[(size_t)(kk + c + 0) * HID];
        const float w1 = W[(size_t)(kk + c + 1) * HID];
        const float w2 = W[(size_t)(kk + c + 2) * HID];
        const float w3 = W[(size_t)(kk + c + 3) * HID];
        #pragma unroll
        for (int r = 0; r < 5; ++r) {
          const float4 s = *(const float4*)&Atile[rbase + r][c];
          acc[r] = fmaf(s.x, w0, fmaf(s.y, w1, fmaf(s.z, w2, fmaf(s.w, w3, acc[r]))));
        }
      }
    }
    #pragma unroll
    for (int r = 0; r < 5; ++r) {
      const int row = rbase + r;
      if (row < KJ) {
        part[((size_t)z * NROWS + n * KJ + row) * 256 + bn * 128 + jj] = acc[r];
      }
    }
  }
  gbar(cnt, 3 * NBLK);      // partials complete

  // ---------------- Stage D: GCN stack (32 active blocks) ------------------
  const int n = blk;
  if (n >= NB) return;

  // adjacency softmax for all 10 gconvs (Ei, Eh[0..7], Eo)
  if (t < 170) {
    const int m = t / KJ, i = t % KJ;
    const float* Es = (m == 0) ? Ei : ((m <= 8) ? Eh + (size_t)(m - 1) * KJ * KJ : Eo);
    const unsigned msk = c_mask[i];
    float mx = -1e30f;
    #pragma unroll
    for (int jj = 0; jj < KJ; ++jj)
      if (msk & (1u << jj)) mx = fmaxf(mx, Es[i * KJ + jj]);
    float ev[KJ];
    float sum = 0.f;
    #pragma unroll
    for (int jj = 0; jj < KJ; ++jj) {
      const float e = (msk & (1u << jj)) ? expf(Es[i * KJ + jj] - mx) : 0.f;
      ev[jj] = e; sum += e;
    }
    const float inv = 1.f / sum;
    #pragma unroll
    for (int jj = 0; jj < KJ; ++jj) adjm[m][i][jj] = ev[jj] * inv;
  }
  // zero pad-rows 17..19
  if (t < 384) { Hs[17 + (t >> 7)][t & 127] = 0.f; Rs[17 + (t >> 7)][t & 127] = 0.f; }

  // sum split-K partials of input gconv h0/h1
  {
    const float* p0 = part + (size_t)(n * KJ) * 256;
    for (int idx = t; idx < KJ * 256; idx += NTHR) {
      const int k = idx >> 8, jj = idx & 255;
      float v = 0.f;
      #pragma unroll
      for (int z = 0; z < SPLITK; ++z)
        v += p0[(size_t)z * NROWS * 256 + k * 256 + jj];
      if (jj < HID) T0s[k][jj] = v; else T1s[k][jj - HID] = v;
    }
  }
  __syncthreads();

  mix_bn<0>(T0s, T1s, adjm[0], bi, gi, bti, Hs, t);
  __syncthreads();

  for (int l = 0; l < 4; ++l) {
    const float* WA = Wh + (size_t)(2 * l) * 2 * HID * HID;
    const float* WB = WA + 2 * HID * HID;
    layer_compute(Hs, WA, T0s, T1s, t);
    __syncthreads();
    mix_bn<0>(T0s, T1s, adjm[1 + 2 * l], bh + (2 * l) * HID, gh + (2 * l) * HID,
              bth + (2 * l) * HID, Rs, t);
    __syncthreads();
    layer_compute(Rs, WB, T0s, T1s, t);
    __syncthreads();
    mix_bn<1>(T0s, T1s, adjm[2 + 2 * l], bh + (2 * l + 1) * HID, gh + (2 * l + 1) * HID,
              bth + (2 * l + 1) * HID, Hs, t);
    __syncthreads();
  }

  // output gconv (no BN/ReLU): 128 -> 3
  if (t < 102) {
    const int p = t / 51, rem = t % 51, i = rem / 3, e = rem % 3;
    const float* Wp = Wo + p * HID * 3 + e;
    float s = 0.f;
    #pragma unroll 4
    for (int c = 0; c < HID; ++c) s = fmaf(Hs[i][c], Wp[c * 3], s);
    if (p == 0) T0s[i][e] = s; else T1s[i][e] = s;
  }
  __syncthreads();
  if (t < 51) {
    const int i = t / 3, e = t % 3;
    const float (*A)[KJ] = adjm[9];
    float s = bo[e];
    #pragma unroll
    for (int jj = 0; jj < KJ; ++jj) s = fmaf(A[i][jj], T1s[jj][e], s);
    s += A[i][i] * (T0s[i][e] - T1s[i][e]);
    out[(n * KJ + i) * 3 + e] = s;
  }
}

// ---------------------------------------------------------------------------
extern "C" void kernel_launch(void* const* d_in, const int* in_sizes, int n_in,
                              void* d_out, int out_size, void* d_ws, size_t ws_size,
                              hipStream_t stream) {
  const float* x       = (const float*)d_in[0];
  const float* heatmap = (const float*)d_in[1];
  const float* bbox    = (const float*)d_in[2];
  const float* pos_w   = (const float*)d_in[3];
  const float* pos_b   = (const float*)d_in[4];
  const float* Wi      = (const float*)d_in[5];
  const float* bi      = (const float*)d_in[6];
  const float* Ei      = (const float*)d_in[7];
  const float* gi      = (const float*)d_in[8];
  const float* bti     = (const float*)d_in[9];
  const float* Wh      = (const float*)d_in[10];
  const float* bh      = (const float*)d_in[11];
  const float* Eh      = (const float*)d_in[12];
  const float* gh      = (const float*)d_in[13];
  const float* bth     = (const float*)d_in[14];
  const float* Wo      = (const float*)d_in[15];
  const float* bo      = (const float*)d_in[16];
  const float* Eo      = (const float*)d_in[17];
  float* out = (float*)d_out;

  // ws layout: cnt (64B) | locs[544] (4KB-aligned block) | h[544*2112] | part[4*544*256]
  unsigned* cnt  = (unsigned*)d_ws;
  int*      locs = (int*)((char*)d_ws + 256);
  float*    h_ws = (float*)((char*)d_ws + 4096);
  float*    part = h_ws + (size_t)NROWS * CEMB;

  k_init<<<1, 64, 0, stream>>>(cnt);
  k_fused<<<NBLK, NTHR, 0, stream>>>(x, heatmap, bbox, pos_w, pos_b, Wi, bi, Ei,
                                     gi, bti, Wh, bh, Eh, gh, bth, Wo, bo, Eo,
                                     cnt, locs, h_ws, part, out);
}